// Round 17
// baseline (516.457 us; speedup 1.0000x reference)
//
#include <hip/hip_runtime.h>

#define NN   100000   // nodes
#define EE   1600000  // edges
#define DD   64       // feature dim
#define DOUT 16       // output dim
#define CAP  64       // CSR slots/node: slot0=self, 1..63 edges, NN-pads to 32/64
#define NPW  8        // nodes per group (W-column amortization quantum — r34 lesson)
#define GPW  2        // groups per wave in k_layer (r35: 16 nodes/wave -> 6250 waves
                      // <= 8192 resident -> ONE occupancy round, zero tail)

// --- build params (r20: 256-node buckets, packed 4B edge records) ---
#define BSH  8                         // bucket = dst >> 8 (256 nodes/bucket)
#define NB   391                       // ceil(100000 / 256)
#define BCAP 5120                      // slots/bucket (Poisson(4096) + 16 sigma)
#define EPB  2048                      // edges per scatter block
#define NBL  ((EE + EPB - 1) / EPB)    // 782 scatter blocks

typedef float v2f __attribute__((ext_vector_type(2)));

// --- bf16 helpers (features stored bf16 — r23 showed fp32 tables double the
// gather line traffic and lose net; ALL arithmetic fp32) ---
__device__ __forceinline__ float lo16(unsigned u) {
    union { unsigned i; float f; } v; v.i = u << 16; return v.f;
}
__device__ __forceinline__ float hi16(unsigned u) {
    union { unsigned i; float f; } v; v.i = u & 0xffff0000u; return v.f;
}
__device__ __forceinline__ float bf2f(unsigned short h) {
    union { unsigned i; float f; } v; v.i = (unsigned)h << 16; return v.f;
}
__device__ __forceinline__ unsigned short f2bf(float f) {   // RNE
    union { float f; unsigned i; } v; v.f = f;
    return (unsigned short)((v.i + 0x7fffu + ((v.i >> 16) & 1u)) >> 16);
}

// ---------------------------------------------------------------------------
// Build K1: one-pass binning scatter. Edge record packed into 4B:
// (src<<8) | (dst & 255); bucket = dst>>8 is implied by the bed region.
// Block 0 zeroes the bf16 sentinel rows (row NN of A and B).
// ---------------------------------------------------------------------------
__global__ __launch_bounds__(256) void k_scatter2(const int* __restrict__ ei,
                                                  int* __restrict__ gcur,
                                                  unsigned* __restrict__ bed,
                                                  unsigned* __restrict__ As,
                                                  unsigned* __restrict__ Bs) {
    if (blockIdx.x == 0) {
        int t = threadIdx.x;
        if (t < 32) As[(size_t)NN * 32 + t] = 0u;
        else if (t < 64) Bs[(size_t)NN * 32 + (t - 32)] = 0u;
    }
    __shared__ int h[NB];
    __shared__ int cur[NB];
    for (int i = threadIdx.x; i < NB; i += 256) h[i] = 0;
    __syncthreads();
    int e0 = blockIdx.x * EPB;
    int e1 = min(e0 + EPB, EE);
    for (int e = e0 + (int)threadIdx.x; e < e1; e += 256)
        atomicAdd(&h[ei[EE + e] >> BSH], 1);
    __syncthreads();
    for (int i = threadIdx.x; i < NB; i += 256)
        cur[i] = i * BCAP + (h[i] ? atomicAdd(&gcur[i], h[i]) : 0);
    __syncthreads();
    for (int e = e0 + (int)threadIdx.x; e < e1; e += 256) {
        int s = ei[e], d = ei[EE + e];
        int b = d >> BSH;
        int p = atomicAdd(&cur[b], 1);
        if (p < (b + 1) * BCAP)                       // 16-sigma guard
            bed[p] = ((unsigned)s << BSH) | (unsigned)(d & (255));
    }
}

// ---------------------------------------------------------------------------
// Build K2 + fused scale: one 512-thread block per 256-node bucket.
// (a) CSR via LDS atomics on the bucket's 256-entry count slice;
// (b) meta phase flattened over (node,slot) pairs — predicated self/pad
//     writes (32/64 pad granularity, matches the GROW gather);
// (c) ts0 = bf16(x * dinv), packed uint stores.
// ---------------------------------------------------------------------------
__global__ __launch_bounds__(512) void k_csr(const unsigned* __restrict__ bed,
                                             const int* __restrict__ gcur,
                                             const float* __restrict__ x,
                                             int* __restrict__ cnt,
                                             int* __restrict__ csr,
                                             unsigned* __restrict__ ts0) {
    __shared__ int lcnt[256];
    int b     = blockIdx.x;
    int nbase = b << BSH;
    int nmax  = min(256, NN - nbase);
    for (int i = threadIdx.x; i < 256; i += 512) lcnt[i] = 0;
    __syncthreads();
    int lo = b * BCAP;
    int hi = lo + min(gcur[b], BCAP);
    for (int e = lo + (int)threadIdx.x; e < hi; e += 512) {
        unsigned v = bed[e];
        int s    = (int)(v >> BSH);
        int doff = (int)(v & 255);
        int pos = atomicAdd(&lcnt[doff], 1);          // LDS atomic
        if (pos < CAP - 1)
            csr[(size_t)(nbase + doff) * CAP + pos + 1] = s;  // slot0=self
    }
    __syncthreads();
    for (int i = threadIdx.x; i < nmax; i += 512)
        cnt[nbase + i] = lcnt[i];
    for (int idx = threadIdx.x; idx < nmax * CAP; idx += 512) {
        int i = idx >> 6, s = idx & 63;
        int c = lcnt[i]; if (c > 63) c = 63;
        int used = 1 + c;
        int end  = (used <= 32) ? 32 : 64;            // r20 granularity (gather-consistent)
        if (s == 0)
            csr[(size_t)(nbase + i) * CAP] = nbase + i;
        else if (s >= used && s < end)
            csr[(size_t)(nbase + i) * CAP + s] = NN;  // zero-sentinel pad
    }
    const float2* xv = (const float2*)x;
    for (int idx = threadIdx.x; idx < nmax * 32; idx += 512) {  // packed uints
        float dv = rsqrtf((float)lcnt[idx >> 5] + 1.0f);
        float2 v = xv[(size_t)nbase * 32 + idx];
        ts0[(size_t)nbase * 32 + idx] =
            (unsigned)f2bf(v.x * dv) | ((unsigned)f2bf(v.y * dv) << 16);
    }
}

// ---------------------------------------------------------------------------
// Gather one node's aggregated row from bf16 rows (128 B/row; lane m loads
// uint2 = feats 4m..4m+3), fp32 accumulate, xor-reduce -> float4 all lanes.
// r25: row indices for slots 0..31 from the wave's prefetched LDS strip.
// r27: v2f accumulators. r31-proven form (r32's finer pads were noise).
// ---------------------------------------------------------------------------
__device__ __forceinline__ float4 gather_node(const uint2* __restrict__ hpv,
                                              const int* cb,
                                              const int* __restrict__ crow,
                                              int c, int sub, int m) {
    v2f fa01 = {0.f, 0.f}, fa23 = {0.f, 0.f};
    v2f fb01 = {0.f, 0.f}, fb23 = {0.f, 0.f};
#define GROW(g, p01, p23)                                                   \
    {                                                                       \
        int row = cb[4 * (g) + sub];                                        \
        uint2 U = hpv[((unsigned)row << 4) + m];                            \
        v2f t0 = {lo16(U.x), hi16(U.x)};                                    \
        v2f t1 = {lo16(U.y), hi16(U.y)};                                    \
        p01 += t0; p23 += t1;                                               \
    }
    GROW(0, fa01, fa23) GROW(1, fb01, fb23) GROW(2, fa01, fa23) GROW(3, fb01, fb23)
    GROW(4, fa01, fa23) GROW(5, fb01, fb23) GROW(6, fa01, fa23) GROW(7, fb01, fb23)
    if (c >= 32) {  // wave-uniform, P ~ 3e-4
#define GROW2(g, p01, p23)                                                  \
        {                                                                   \
            int row = crow[32 + 4 * (g) + sub];                             \
            uint2 U = hpv[((unsigned)row << 4) + m];                        \
            v2f t0 = {lo16(U.x), hi16(U.x)};                                \
            v2f t1 = {lo16(U.y), hi16(U.y)};                                \
            p01 += t0; p23 += t1;                                           \
        }
        GROW2(0, fa01, fa23) GROW2(1, fb01, fb23) GROW2(2, fa01, fa23) GROW2(3, fb01, fb23)
        GROW2(4, fa01, fa23) GROW2(5, fb01, fb23) GROW2(6, fa01, fa23) GROW2(7, fb01, fb23)
#undef GROW2
    }
#undef GROW
    v2f s01 = fa01 + fb01, s23 = fa23 + fb23;
    float4 s;
    s.x = s01.x; s.y = s01.y; s.z = s23.x; s.w = s23.y;
    s.x += __shfl_xor(s.x, 16); s.y += __shfl_xor(s.y, 16);
    s.z += __shfl_xor(s.z, 16); s.w += __shfl_xor(s.w, 16);
    s.x += __shfl_xor(s.x, 32); s.y += __shfl_xor(s.y, 32);
    s.z += __shfl_xor(s.z, 32); s.w += __shfl_xor(s.w, 32);
    return s;
}

// ---------------------------------------------------------------------------
// GCN layer (all 3 layers), r35: ONE-ROUND GRID. 16 nodes/wave as GPW=2
// sequential groups of NPW=8 (group body = r33's proven kernel body,
// including per-group streamed W loads — r34 showed halving the W
// amortization quantum costs more than the tail saves). 6250 working waves
// <= 8192 resident slots at the (256,8) bound -> all blocks co-resident,
// zero drain tail, constant ~76% occupancy (r33 time-averaged 58% over
// 1.53 rounds). 100000/16 = 6250 exactly -> overshoot waves (2 of 6252)
// exit whole at the top; no partial groups. The in-loop memory-clobber
// fence also blocks LICM from hoisting W loads across group 2's gathers
// (the r26 demotion failure). r28/r29 lesson: no FFN fusion here.
// ---------------------------------------------------------------------------
template <int SCALE>
__global__ __launch_bounds__(256, 8) void k_layer(const unsigned short* __restrict__ tsin,
                                                  const int* __restrict__ csr,
                                                  const int* __restrict__ cnt,
                                                  const float* __restrict__ bias,
                                                  const float* __restrict__ W,
                                                  unsigned short* __restrict__ outp) {
    __shared__ float tb[4][NPW][DD];     // 8192 B  (agg rows, per wave, per-group reuse)
    __shared__ float dvb[4][NPW];        // 128 B   (per-node dinv)
    __shared__ int   cbuf[4][NPW * 32];  // 4096 B  (per-wave CSR strip, per-group reuse)
    const int lane = threadIdx.x & 63;
    const int wv   = threadIdx.x >> 6;
    const int sub  = lane >> 4;
    const int m    = lane & 15;

    int base0 = (blockIdx.x * 4 + wv) * (GPW * NPW);  // 1563 blocks; waves 6250/6252 work
    if (base0 >= NN) return;                          // whole-wave overshoot only

    const float bv = bias[lane];
    const uint2* hpv = (const uint2*)tsin;

#pragma unroll 1
    for (int g = 0; g < GPW; ++g) {
        int base = base0 + g * NPW;

        // ---- CSR strip prefetch: lane l -> node base+(l>>3), quad l&7 ----
        {
            const int4* cg4 = (const int4*)csr;
            int4 U = cg4[((size_t)(base + (lane >> 3)) << 4) + (lane & 7)];
            ((int4*)cbuf[wv])[lane] = U;
        }

        // ---- phase 1: 8 serial gathers (r20 schedule) ----
        for (int r = 0; r < NPW; ++r) {
            int n = base + r;
            int c = cnt[n]; if (c > 63) c = 63;
            float dv = rsqrtf((float)cnt[n] + 1.0f);
            float4 s = gather_node(hpv, cbuf[wv] + r * 32,
                                   csr + (size_t)n * CAP, c, sub, m);
            if (sub == 0) {
                ((float4*)tb[wv][r])[m] = s;      // agg row -> wave slot
                if (m == 0) dvb[wv][r] = dv;
            }
        }

        asm volatile("" ::: "memory");   // keep W loads below the gathers (per group)

        // ---- phase 2: streamed W column (r33-proven; VGPR stays ~32) ----
        float wreg[DD];
#pragma unroll
        for (int k = 0; k < DD; ++k) wreg[k] = W[k * DD + lane];

        float o[NPW];
#pragma unroll
        for (int r = 0; r < NPW; ++r) o[r] = 0.f;
#pragma unroll
        for (int kk = 0; kk < DD / 4; ++kk) {
#pragma unroll
            for (int r = 0; r < NPW; ++r) {
                float4 q = ((const float4*)tb[wv][r])[kk];   // wave-uniform broadcast
                o[r] = fmaf(q.x, wreg[4 * kk + 0],
                       fmaf(q.y, wreg[4 * kk + 1],
                       fmaf(q.z, wreg[4 * kk + 2],
                       fmaf(q.w, wreg[4 * kk + 3], o[r]))));
            }
        }

        // ---- epilogue: bias+relu+scale, bf16 stores ----
#pragma unroll
        for (int r = 0; r < NPW; ++r) {
            float dv = dvb[wv][r];
            float t  = fmaxf(fmaf(dv, o[r], bv), 0.f);
            outp[(size_t)(base + r) * DD + lane] = f2bf(SCALE ? t * dv : t);
        }
    }
}

// ---------------------------------------------------------------------------
// Dense FFN, r31-proven: barrier-free (zero conflicts, LDS 8.2KB), (256,2)
// register budget — r18/r30 scar: the wreg1[64]+u+p+W2reg live set is ~110
// VGPRs; any tighter bound spills ~110MB of scratch.
// ---------------------------------------------------------------------------
__global__ __launch_bounds__(256, 2) void k_ffn(const unsigned short* __restrict__ t3,
                                                const float* __restrict__ Wf1,
                                                const float* __restrict__ bf1,
                                                const float* __restrict__ Wf2,
                                                const float* __restrict__ bf2,
                                                float* __restrict__ out) {
    __shared__ float tb8[4][NPW][DD];    // 8192 B (t rows, then u rows)
    const int lane = threadIdx.x & 63;
    const int wv   = threadIdx.x >> 6;
    const int sub  = lane >> 4;   // K-quarter for the 2nd matmul
    const int m    = lane & 15;

    int base = (blockIdx.x * 4 + wv) * NPW;   // exact cover

    // ---- stage 8 bf16 t rows (wave-local; co-issues with Wf1 loads) ----
#pragma unroll
    for (int r = 0; r < NPW; ++r)
        tb8[wv][r][lane] = bf2f(t3[(size_t)(base + r) * DD + lane]);

    // ---- Wf1 column -> registers (lane j reads Wf1[k][j], coalesced) ----
    float wreg1[DD];
#pragma unroll
    for (int k = 0; k < DD; ++k) wreg1[k] = Wf1[k * DD + lane];

    const float b1v = bf1[lane];

    // ---- batched matmul1: u = relu(t @ Wf1 + bf1) ----
    float u[NPW];
#pragma unroll
    for (int r = 0; r < NPW; ++r) u[r] = b1v;
#pragma unroll
    for (int kk = 0; kk < DD / 4; ++kk) {
#pragma unroll
        for (int r = 0; r < NPW; ++r) {
            float4 q = ((const float4*)tb8[wv][r])[kk];  // uniform broadcast
            u[r] = fmaf(q.x, wreg1[4 * kk + 0],
                   fmaf(q.y, wreg1[4 * kk + 1],
                   fmaf(q.z, wreg1[4 * kk + 2],
                   fmaf(q.w, wreg1[4 * kk + 3], u[r]))));
        }
    }
#pragma unroll
    for (int r = 0; r < NPW; ++r)
        tb8[wv][r][lane] = fmaxf(u[r], 0.f);   // u rows overwrite t rows

    asm volatile("" ::: "memory");   // keep W2reg loads below mm1

    // ---- batched matmul2: out = u @ Wf2 + bf2 (K-quarter split) ----
    float W2reg[16];
#pragma unroll
    for (int kk = 0; kk < 16; ++kk) W2reg[kk] = Wf2[(sub * 16 + kk) * DOUT + m];
    const float b2v = bf2[m];

    float p[NPW];
#pragma unroll
    for (int r = 0; r < NPW; ++r) p[r] = 0.f;
#pragma unroll
    for (int kq = 0; kq < 4; ++kq) {
        float a0 = W2reg[4 * kq + 0], a1 = W2reg[4 * kq + 1];
        float a2 = W2reg[4 * kq + 2], a3 = W2reg[4 * kq + 3];
#pragma unroll
        for (int r = 0; r < NPW; ++r) {
            float4 z = ((const float4*)(tb8[wv][r] + sub * 16))[kq];
            p[r] = fmaf(z.x, a0, fmaf(z.y, a1, fmaf(z.z, a2, fmaf(z.w, a3, p[r]))));
        }
    }
#pragma unroll
    for (int r = 0; r < NPW; ++r) {
        p[r] += __shfl_xor(p[r], 16);
        p[r] += __shfl_xor(p[r], 32);
        if (lane < 16) out[(size_t)(base + r) * DOUT + m] = p[r] + b2v;
    }
}

// ---------------------------------------------------------------------------
extern "C" void kernel_launch(void* const* d_in, const int* in_sizes, int n_in,
                              void* d_out, int out_size, void* d_ws, size_t ws_size,
                              hipStream_t stream) {
    const float* x   = (const float*)d_in[0];
    const int*   ei  = (const int*)d_in[1];
    const float* W1  = (const float*)d_in[2];
    const float* b1  = (const float*)d_in[3];
    const float* W2  = (const float*)d_in[4];
    const float* b2  = (const float*)d_in[5];
    const float* W3  = (const float*)d_in[6];
    const float* b3  = (const float*)d_in[7];
    const float* Wf1 = (const float*)d_in[8];
    const float* bf1 = (const float*)d_in[9];
    const float* Wf2 = (const float*)d_in[10];
    const float* bf2 = (const float*)d_in[11];
    float* out = (float*)d_out;

    char* ws = (char*)d_ws;
    auto al = [](size_t v) { return (v + 255) & ~(size_t)255; };
    size_t off = 0;
    int* cnt  = (int*)(ws + off);              off = al(off + (size_t)NN * 4);
    int* gcur = (int*)(ws + off);              off = al(off + (size_t)NB * 4);
    int* csr  = (int*)(ws + off);              off = al(off + (size_t)NN * CAP * 4);
    unsigned short* A = (unsigned short*)(ws + off); off = al(off + (size_t)(NN + 1) * DD * 2);
    unsigned short* B = (unsigned short*)(ws + off); off = al(off + (size_t)(NN + 1) * DD * 2);
    unsigned* bed = (unsigned*)(ws + off);     off = al(off + (size_t)NB * BCAP * 4);

    hipMemsetAsync(gcur, 0, (size_t)NB * 4, stream);
    k_scatter2<<<NBL, 256, 0, stream>>>(ei, gcur, bed, (unsigned*)A, (unsigned*)B);
    // CSR (self + edges + sentinel pads, LDS atomics) + fused ts0 -> A
    k_csr<<<NB, 512, 0, stream>>>(bed, gcur, x, cnt, csr, (unsigned*)A);

    int gl = (NN + 4 * GPW * NPW - 1) / (4 * GPW * NPW);  // 1563 blocks, one round
    int gf = NN / (4 * NPW);                              // 3125 blocks

    // layer 1: ts1 = bf16(relu(dinv*(agg(ts0)@W1)+b1)*dinv) -> B
    k_layer<1><<<gl, 256, 0, stream>>>(A, csr, cnt, b1, W1, B);
    // layer 2: ts2 -> A
    k_layer<1><<<gl, 256, 0, stream>>>(B, csr, cnt, b2, W2, A);
    // layer 3: t3 = bf16(relu(dinv*(agg(ts2)@W3)+b3)), UNSCALED -> B
    k_layer<0><<<gl, 256, 0, stream>>>(A, csr, cnt, b3, W3, B);
    // FFN: out = relu(t3@Wf1+bf1)@Wf2 + bf2
    k_ffn<<<gf, 256, 0, stream>>>(B, Wf1, bf1, Wf2, bf2, out);
}

// Round 18
// 291.933 us; speedup vs baseline: 1.7691x; 1.7691x over previous
//
#include <hip/hip_runtime.h>

#define NN   100000   // nodes
#define EE   1600000  // edges
#define DD   64       // feature dim
#define DOUT 16       // output dim
#define CAP  64       // CSR slots/node: slot0=self, 1..63 edges, NN-pads to 32/64
#define NPW  8        // nodes per wave (r20 structure; gathers strictly serial)

// --- build params (r20: 256-node buckets, packed 4B edge records) ---
#define BSH  8                         // bucket = dst >> 8 (256 nodes/bucket)
#define NB   391                       // ceil(100000 / 256)
#define BCAP 5120                      // slots/bucket (Poisson(4096) + 16 sigma)
#define EPB  2048                      // edges per scatter block
#define NBL  ((EE + EPB - 1) / EPB)    // 782 scatter blocks

typedef float v2f __attribute__((ext_vector_type(2)));

// --- bf16 helpers (features stored bf16 — r23 showed fp32 tables double the
// gather line traffic and lose net; ALL arithmetic fp32) ---
__device__ __forceinline__ float lo16(unsigned u) {
    union { unsigned i; float f; } v; v.i = u << 16; return v.f;
}
__device__ __forceinline__ float hi16(unsigned u) {
    union { unsigned i; float f; } v; v.i = u & 0xffff0000u; return v.f;
}
__device__ __forceinline__ float bf2f(unsigned short h) {
    union { unsigned i; float f; } v; v.i = (unsigned)h << 16; return v.f;
}
__device__ __forceinline__ unsigned short f2bf(float f) {   // RNE
    union { float f; unsigned i; } v; v.f = f;
    return (unsigned short)((v.i + 0x7fffu + ((v.i >> 16) & 1u)) >> 16);
}

// ---------------------------------------------------------------------------
// Build K1: one-pass binning scatter. Edge record packed into 4B:
// (src<<8) | (dst & 255); bucket = dst>>8 is implied by the bed region.
// Block 0 zeroes the bf16 sentinel rows (row NN of A and B).
// ---------------------------------------------------------------------------
__global__ __launch_bounds__(256) void k_scatter2(const int* __restrict__ ei,
                                                  int* __restrict__ gcur,
                                                  unsigned* __restrict__ bed,
                                                  unsigned* __restrict__ As,
                                                  unsigned* __restrict__ Bs) {
    if (blockIdx.x == 0) {
        int t = threadIdx.x;
        if (t < 32) As[(size_t)NN * 32 + t] = 0u;
        else if (t < 64) Bs[(size_t)NN * 32 + (t - 32)] = 0u;
    }
    __shared__ int h[NB];
    __shared__ int cur[NB];
    for (int i = threadIdx.x; i < NB; i += 256) h[i] = 0;
    __syncthreads();
    int e0 = blockIdx.x * EPB;
    int e1 = min(e0 + EPB, EE);
    for (int e = e0 + (int)threadIdx.x; e < e1; e += 256)
        atomicAdd(&h[ei[EE + e] >> BSH], 1);
    __syncthreads();
    for (int i = threadIdx.x; i < NB; i += 256)
        cur[i] = i * BCAP + (h[i] ? atomicAdd(&gcur[i], h[i]) : 0);
    __syncthreads();
    for (int e = e0 + (int)threadIdx.x; e < e1; e += 256) {
        int s = ei[e], d = ei[EE + e];
        int b = d >> BSH;
        int p = atomicAdd(&cur[b], 1);
        if (p < (b + 1) * BCAP)                       // 16-sigma guard
            bed[p] = ((unsigned)s << BSH) | (unsigned)(d & (255));
    }
}

// ---------------------------------------------------------------------------
// Build K2 + fused scale: one 512-thread block per 256-node bucket.
// (a) CSR via LDS atomics on the bucket's 256-entry count slice;
// (b) meta phase flattened over (node,slot) pairs — predicated self/pad
//     writes (32/64 pad granularity, matches the GROW gather);
// (c) ts0 = bf16(x * dinv), packed uint stores.
// ---------------------------------------------------------------------------
__global__ __launch_bounds__(512) void k_csr(const unsigned* __restrict__ bed,
                                             const int* __restrict__ gcur,
                                             const float* __restrict__ x,
                                             int* __restrict__ cnt,
                                             int* __restrict__ csr,
                                             unsigned* __restrict__ ts0) {
    __shared__ int lcnt[256];
    int b     = blockIdx.x;
    int nbase = b << BSH;
    int nmax  = min(256, NN - nbase);
    for (int i = threadIdx.x; i < 256; i += 512) lcnt[i] = 0;
    __syncthreads();
    int lo = b * BCAP;
    int hi = lo + min(gcur[b], BCAP);
    for (int e = lo + (int)threadIdx.x; e < hi; e += 512) {
        unsigned v = bed[e];
        int s    = (int)(v >> BSH);
        int doff = (int)(v & 255);
        int pos = atomicAdd(&lcnt[doff], 1);          // LDS atomic
        if (pos < CAP - 1)
            csr[(size_t)(nbase + doff) * CAP + pos + 1] = s;  // slot0=self
    }
    __syncthreads();
    for (int i = threadIdx.x; i < nmax; i += 512)
        cnt[nbase + i] = lcnt[i];
    for (int idx = threadIdx.x; idx < nmax * CAP; idx += 512) {
        int i = idx >> 6, s = idx & 63;
        int c = lcnt[i]; if (c > 63) c = 63;
        int used = 1 + c;
        int end  = (used <= 32) ? 32 : 64;            // r20 granularity (gather-consistent)
        if (s == 0)
            csr[(size_t)(nbase + i) * CAP] = nbase + i;
        else if (s >= used && s < end)
            csr[(size_t)(nbase + i) * CAP + s] = NN;  // zero-sentinel pad
    }
    const float2* xv = (const float2*)x;
    for (int idx = threadIdx.x; idx < nmax * 32; idx += 512) {  // packed uints
        float dv = rsqrtf((float)lcnt[idx >> 5] + 1.0f);
        float2 v = xv[(size_t)nbase * 32 + idx];
        ts0[(size_t)nbase * 32 + idx] =
            (unsigned)f2bf(v.x * dv) | ((unsigned)f2bf(v.y * dv) << 16);
    }
}

// ---------------------------------------------------------------------------
// Gather one node's aggregated row from bf16 rows (128 B/row; lane m loads
// uint2 = feats 4m..4m+3), fp32 accumulate, xor-reduce -> float4 all lanes.
// r25: row indices for slots 0..31 from the wave's prefetched LDS strip.
// r27: v2f accumulators. r31-proven form (r32's finer pads were noise).
// ---------------------------------------------------------------------------
__device__ __forceinline__ float4 gather_node(const uint2* __restrict__ hpv,
                                              const int* cb,
                                              const int* __restrict__ crow,
                                              int c, int sub, int m) {
    v2f fa01 = {0.f, 0.f}, fa23 = {0.f, 0.f};
    v2f fb01 = {0.f, 0.f}, fb23 = {0.f, 0.f};
#define GROW(g, p01, p23)                                                   \
    {                                                                       \
        int row = cb[4 * (g) + sub];                                        \
        uint2 U = hpv[((unsigned)row << 4) + m];                            \
        v2f t0 = {lo16(U.x), hi16(U.x)};                                    \
        v2f t1 = {lo16(U.y), hi16(U.y)};                                    \
        p01 += t0; p23 += t1;                                               \
    }
    GROW(0, fa01, fa23) GROW(1, fb01, fb23) GROW(2, fa01, fa23) GROW(3, fb01, fb23)
    GROW(4, fa01, fa23) GROW(5, fb01, fb23) GROW(6, fa01, fa23) GROW(7, fb01, fb23)
    if (c >= 32) {  // wave-uniform, P ~ 3e-4
#define GROW2(g, p01, p23)                                                  \
        {                                                                   \
            int row = crow[32 + 4 * (g) + sub];                             \
            uint2 U = hpv[((unsigned)row << 4) + m];                        \
            v2f t0 = {lo16(U.x), hi16(U.x)};                                \
            v2f t1 = {lo16(U.y), hi16(U.y)};                                \
            p01 += t0; p23 += t1;                                           \
        }
        GROW2(0, fa01, fa23) GROW2(1, fb01, fb23) GROW2(2, fa01, fa23) GROW2(3, fb01, fb23)
        GROW2(4, fa01, fa23) GROW2(5, fb01, fb23) GROW2(6, fa01, fa23) GROW2(7, fb01, fb23)
#undef GROW2
    }
#undef GROW
    v2f s01 = fa01 + fb01, s23 = fa23 + fb23;
    float4 s;
    s.x = s01.x; s.y = s01.y; s.z = s23.x; s.w = s23.y;
    s.x += __shfl_xor(s.x, 16); s.y += __shfl_xor(s.y, 16);
    s.z += __shfl_xor(s.z, 16); s.w += __shfl_xor(s.w, 16);
    s.x += __shfl_xor(s.x, 32); s.y += __shfl_xor(s.y, 32);
    s.z += __shfl_xor(s.z, 32); s.w += __shfl_xor(s.w, 32);
    return s;
}

// ---------------------------------------------------------------------------
// GCN layer (all 3 layers), r33-proven (292.7us total, best verified):
// barrier-free, CSR strip prefetch, W column loaded into registers AFTER
// phase 1 (fence pins the live range; allocator streams the loads into
// phase 2 — VGPR=32, zero conflicts), (256,8) bound (occupancy 58%).
// HARD CONSTRAINT (r26/r29/r35 scars): wreg[64] must live in a
// straight-line once-executed body — hoisting (demote), tight caps (spill),
// and loop-wrapping (scratch, 137MB WRITE signature) all break it.
// Tail fixes failed twice: NPL=4 doubles W traffic (r34); GPW loop
// demotes wreg (r35). 58% occupancy is this structure's boundary.
// r28/r29 lesson: do NOT fuse the FFN here (64-reg cliff / spill).
// ---------------------------------------------------------------------------
template <int SCALE>
__global__ __launch_bounds__(256, 8) void k_layer(const unsigned short* __restrict__ tsin,
                                                  const int* __restrict__ csr,
                                                  const int* __restrict__ cnt,
                                                  const float* __restrict__ bias,
                                                  const float* __restrict__ W,
                                                  unsigned short* __restrict__ outp) {
    __shared__ float tb[4][NPW][DD];     // 8192 B  (agg rows, per wave)
    __shared__ float dvb[4][NPW];        // 128 B   (per-node dinv)
    __shared__ int   cbuf[4][NPW * 32];  // 4096 B  (per-wave CSR strip)
    const int lane = threadIdx.x & 63;
    const int wv   = threadIdx.x >> 6;
    const int sub  = lane >> 4;
    const int m    = lane & 15;

    int base = (blockIdx.x * 4 + wv) * NPW;   // 3125 blocks * 32 = 100000 exact

    {
        const int4* cg4 = (const int4*)csr;
        int4 U = cg4[((size_t)(base + (lane >> 3)) << 4) + (lane & 7)];
        ((int4*)cbuf[wv])[lane] = U;
    }

    const float bv = bias[lane];
    const uint2* hpv = (const uint2*)tsin;

    for (int r = 0; r < NPW; ++r) {
        int n = base + r;
        if (n >= NN) return;
        int c = cnt[n]; if (c > 63) c = 63;
        float dv = rsqrtf((float)cnt[n] + 1.0f);
        float4 s = gather_node(hpv, cbuf[wv] + r * 32,
                               csr + (size_t)n * CAP, c, sub, m);
        if (sub == 0) {
            ((float4*)tb[wv][r])[m] = s;      // agg row -> wave slot
            if (m == 0) dvb[wv][r] = dv;
        }
    }

    asm volatile("" ::: "memory");   // keep W loads below the gather loop

    float wreg[DD];
#pragma unroll
    for (int k = 0; k < DD; ++k) wreg[k] = W[k * DD + lane];

    float o[NPW];
#pragma unroll
    for (int r = 0; r < NPW; ++r) o[r] = 0.f;
#pragma unroll
    for (int kk = 0; kk < DD / 4; ++kk) {
#pragma unroll
        for (int r = 0; r < NPW; ++r) {
            float4 q = ((const float4*)tb[wv][r])[kk];   // wave-uniform broadcast
            o[r] = fmaf(q.x, wreg[4 * kk + 0],
                   fmaf(q.y, wreg[4 * kk + 1],
                   fmaf(q.z, wreg[4 * kk + 2],
                   fmaf(q.w, wreg[4 * kk + 3], o[r]))));
        }
    }

#pragma unroll
    for (int r = 0; r < NPW; ++r) {
        float dv = dvb[wv][r];
        float t  = fmaxf(fmaf(dv, o[r], bv), 0.f);
        outp[(size_t)(base + r) * DD + lane] = f2bf(SCALE ? t * dv : t);
    }
}

// ---------------------------------------------------------------------------
// Dense FFN, r31-proven: barrier-free (zero conflicts, LDS 8.2KB), (256,2)
// register budget — r18/r30 scar: the wreg1[64]+u+p+W2reg live set is ~110
// VGPRs; any tighter bound spills ~110MB of scratch.
// ---------------------------------------------------------------------------
__global__ __launch_bounds__(256, 2) void k_ffn(const unsigned short* __restrict__ t3,
                                                const float* __restrict__ Wf1,
                                                const float* __restrict__ bf1,
                                                const float* __restrict__ Wf2,
                                                const float* __restrict__ bf2,
                                                float* __restrict__ out) {
    __shared__ float tb8[4][NPW][DD];    // 8192 B (t rows, then u rows)
    const int lane = threadIdx.x & 63;
    const int wv   = threadIdx.x >> 6;
    const int sub  = lane >> 4;   // K-quarter for the 2nd matmul
    const int m    = lane & 15;

    int base = (blockIdx.x * 4 + wv) * NPW;   // exact cover

    // ---- stage 8 bf16 t rows (wave-local; co-issues with Wf1 loads) ----
#pragma unroll
    for (int r = 0; r < NPW; ++r)
        tb8[wv][r][lane] = bf2f(t3[(size_t)(base + r) * DD + lane]);

    // ---- Wf1 column -> registers (lane j reads Wf1[k][j], coalesced) ----
    float wreg1[DD];
#pragma unroll
    for (int k = 0; k < DD; ++k) wreg1[k] = Wf1[k * DD + lane];

    const float b1v = bf1[lane];

    // ---- batched matmul1: u = relu(t @ Wf1 + bf1) ----
    float u[NPW];
#pragma unroll
    for (int r = 0; r < NPW; ++r) u[r] = b1v;
#pragma unroll
    for (int kk = 0; kk < DD / 4; ++kk) {
#pragma unroll
        for (int r = 0; r < NPW; ++r) {
            float4 q = ((const float4*)tb8[wv][r])[kk];  // uniform broadcast
            u[r] = fmaf(q.x, wreg1[4 * kk + 0],
                   fmaf(q.y, wreg1[4 * kk + 1],
                   fmaf(q.z, wreg1[4 * kk + 2],
                   fmaf(q.w, wreg1[4 * kk + 3], u[r]))));
        }
    }
#pragma unroll
    for (int r = 0; r < NPW; ++r)
        tb8[wv][r][lane] = fmaxf(u[r], 0.f);   // u rows overwrite t rows

    asm volatile("" ::: "memory");   // keep W2reg loads below mm1

    // ---- batched matmul2: out = u @ Wf2 + bf2 (K-quarter split) ----
    float W2reg[16];
#pragma unroll
    for (int kk = 0; kk < 16; ++kk) W2reg[kk] = Wf2[(sub * 16 + kk) * DOUT + m];
    const float b2v = bf2[m];

    float p[NPW];
#pragma unroll
    for (int r = 0; r < NPW; ++r) p[r] = 0.f;
#pragma unroll
    for (int kq = 0; kq < 4; ++kq) {
        float a0 = W2reg[4 * kq + 0], a1 = W2reg[4 * kq + 1];
        float a2 = W2reg[4 * kq + 2], a3 = W2reg[4 * kq + 3];
#pragma unroll
        for (int r = 0; r < NPW; ++r) {
            float4 z = ((const float4*)(tb8[wv][r] + sub * 16))[kq];
            p[r] = fmaf(z.x, a0, fmaf(z.y, a1, fmaf(z.z, a2, fmaf(z.w, a3, p[r]))));
        }
    }
#pragma unroll
    for (int r = 0; r < NPW; ++r) {
        p[r] += __shfl_xor(p[r], 16);
        p[r] += __shfl_xor(p[r], 32);
        if (lane < 16) out[(size_t)(base + r) * DOUT + m] = p[r] + b2v;
    }
}

// ---------------------------------------------------------------------------
extern "C" void kernel_launch(void* const* d_in, const int* in_sizes, int n_in,
                              void* d_out, int out_size, void* d_ws, size_t ws_size,
                              hipStream_t stream) {
    const float* x   = (const float*)d_in[0];
    const int*   ei  = (const int*)d_in[1];
    const float* W1  = (const float*)d_in[2];
    const float* b1  = (const float*)d_in[3];
    const float* W2  = (const float*)d_in[4];
    const float* b2  = (const float*)d_in[5];
    const float* W3  = (const float*)d_in[6];
    const float* b3  = (const float*)d_in[7];
    const float* Wf1 = (const float*)d_in[8];
    const float* bf1 = (const float*)d_in[9];
    const float* Wf2 = (const float*)d_in[10];
    const float* bf2 = (const float*)d_in[11];
    float* out = (float*)d_out;

    char* ws = (char*)d_ws;
    auto al = [](size_t v) { return (v + 255) & ~(size_t)255; };
    size_t off = 0;
    int* cnt  = (int*)(ws + off);              off = al(off + (size_t)NN * 4);
    int* gcur = (int*)(ws + off);              off = al(off + (size_t)NB * 4);
    int* csr  = (int*)(ws + off);              off = al(off + (size_t)NN * CAP * 4);
    unsigned short* A = (unsigned short*)(ws + off); off = al(off + (size_t)(NN + 1) * DD * 2);
    unsigned short* B = (unsigned short*)(ws + off); off = al(off + (size_t)(NN + 1) * DD * 2);
    unsigned* bed = (unsigned*)(ws + off);     off = al(off + (size_t)NB * BCAP * 4);

    hipMemsetAsync(gcur, 0, (size_t)NB * 4, stream);
    k_scatter2<<<NBL, 256, 0, stream>>>(ei, gcur, bed, (unsigned*)A, (unsigned*)B);
    // CSR (self + edges + sentinel pads, LDS atomics) + fused ts0 -> A
    k_csr<<<NB, 512, 0, stream>>>(bed, gcur, x, cnt, csr, (unsigned*)A);

    int gf = NN / (4 * NPW);                       // 3125 blocks, exact cover

    // layer 1: ts1 = bf16(relu(dinv*(agg(ts0)@W1)+b1)*dinv) -> B
    k_layer<1><<<gf, 256, 0, stream>>>(A, csr, cnt, b1, W1, B);
    // layer 2: ts2 -> A
    k_layer<1><<<gf, 256, 0, stream>>>(B, csr, cnt, b2, W2, A);
    // layer 3: t3 = bf16(relu(dinv*(agg(ts2)@W3)+b3)), UNSCALED -> B
    k_layer<0><<<gf, 256, 0, stream>>>(A, csr, cnt, b3, W3, B);
    // FFN: out = relu(t3@Wf1+bf1)@Wf2 + bf2
    k_ffn<<<gf, 256, 0, stream>>>(B, Wf1, bf1, Wf2, bf2, out);
}